// Round 8
// baseline (153.519 us; speedup 1.0000x reference)
//
#include <hip/hip_runtime.h>
#include <hip/hip_bf16.h>

typedef short bf16x8 __attribute__((ext_vector_type(8)));
typedef short bf16x4 __attribute__((ext_vector_type(4)));
typedef float f32x4 __attribute__((ext_vector_type(4)));

#define T_DIM 2048
#define D_DIM 64
#define BH 32
#define NELEM (BH * T_DIM * D_DIM)   // 4194304 elements per tensor
#define WIN 128
#define QBLK 64
#define ACCT 17          // max live 16-wide k-tiles per 16-row wave tile
#define NEGBIG -1e30f

__device__ __forceinline__ short f2b(float x) {
  __hip_bfloat16 h = __float2bfloat16(x);
  return *reinterpret_cast<short*>(&h);
}
__device__ __forceinline__ float b2f(short s) {
  unsigned u = ((unsigned)(unsigned short)s) << 16;
  return __builtin_bit_cast(float, u);
}
__device__ __forceinline__ bf16x8 cvt8(f32x4 a, f32x4 b) {
  bf16x8 r;
  r[0] = f2b(a[0]); r[1] = f2b(a[1]); r[2] = f2b(a[2]); r[3] = f2b(a[3]);
  r[4] = f2b(b[0]); r[5] = f2b(b[1]); r[6] = f2b(b[2]); r[7] = f2b(b[3]);
  return r;
}
// swizzled byte address in a 640B-row LDS tile
__device__ __forceinline__ int swz(int row, int b) { return row * 640 + (b ^ ((row & 7) << 4)); }

// ---------------- prepass: f32 -> bf16 copy (Q, K) ----------------
__global__ __launch_bounds__(256) void conv_qk(const float* __restrict__ A,
                                               short* __restrict__ B) {
  const size_t i = ((size_t)blockIdx.x * 256 + threadIdx.x) * 8;
  const f32x4 a = *(const f32x4*)(A + i);
  const f32x4 b = *(const f32x4*)(A + i + 4);
  *(bf16x8*)(B + i) = cvt8(a, b);
}

// ---------------- prepass: V -> V^T bf16 (per-bh [64][2048]) ----------------
__global__ __launch_bounds__(256) void conv_vt(const float* __restrict__ V,
                                               short* __restrict__ Vt) {
  __shared__ short Lt[64][65];
  const int bh = blockIdx.x >> 5, k0 = (blockIdx.x & 31) * 64;
  const int tid = threadIdx.x;
  {
    const int kr = tid >> 2, dq = tid & 3;
    const float* src = V + ((size_t)(bh * T_DIM + k0 + kr)) * D_DIM + dq * 16;
#pragma unroll
    for (int g = 0; g < 4; ++g) {
      const f32x4 f = *(const f32x4*)(src + g * 4);
#pragma unroll
      for (int j = 0; j < 4; ++j) Lt[kr][dq * 16 + g * 4 + j] = f2b(f[j]);
    }
  }
  __syncthreads();
  {
    const int dr = tid >> 2, kc = tid & 3;
    bf16x8 o0, o1;
#pragma unroll
    for (int j = 0; j < 8; ++j) {
      o0[j] = Lt[kc * 16 + j][dr];
      o1[j] = Lt[kc * 16 + 8 + j][dr];
    }
    short* dst = Vt + ((size_t)(bh * D_DIM + dr)) * T_DIM + k0 + kc * 16;
    *(bf16x8*)dst = o0;
    *(bf16x8*)(dst + 8) = o1;
  }
}

// ---------------- main: barrier-free banded attention ----------------
__global__ __launch_bounds__(256, 3) void lsa_main(
    const short* __restrict__ Q16, const short* __restrict__ K16,
    const short* __restrict__ Vt16, float* __restrict__ Og, float* __restrict__ Ag) {
  const int tid = threadIdx.x;
  // XCD-chunked swizzle
  const int work = ((blockIdx.x & 7) << 7) + (blockIdx.x >> 3);
  const int bh = work >> 5;
  const int q0 = (work & 31) * QBLK;
  int kstart = q0 - WIN; if (kstart < 0) kstart = 0;
  int kend = q0 + QBLK + WIN; if (kend > T_DIM) kend = T_DIM;
  const int nkt = (kend - kstart) >> 4;

  float* optr = Og + (size_t)bh * (T_DIM * D_DIM);
  float* aptr = Ag + (size_t)bh * ((size_t)T_DIM * T_DIM);

  // LDS: P band only, 40KB -> 3 blocks/CU (VGPR-capped), no barriers at all
  __shared__ __align__(16) char Pb[QBLK * 640];

  const int lane = tid & 63, w = tid >> 6, c = lane & 15, hi = lane >> 4;

  // Q B-frag (swapped QK^T): lane holds Q row q0+w*16+c
  const short* qp = Q16 + ((size_t)(bh * T_DIM + q0 + w * 16 + c)) * D_DIM + 8 * hi;
  const bf16x8 qb0 = *(const bf16x8*)qp;
  const bf16x8 qb1 = *(const bf16x8*)(qp + 32);

  // per-wave live tile range
  int klo = q0 + w * 16 - WIN - kstart; if (klo < 0) klo = 0;
  const int kt0 = klo >> 4;
  int kt1 = (q0 + w * 16 + 15 + WIN + 1 - kstart + 15) >> 4; if (kt1 > nkt) kt1 = nkt;
  const int s0 = kt0 >> 1, s1 = (kt1 + 1) >> 1;
  const int nlive = kt1 - kt0;

  // ---- S^T = K Q^T over live tiles ----
  f32x4 acc[ACCT];
  const short* kbase = K16 + ((size_t)(bh * T_DIM + kstart + c)) * D_DIM + 8 * hi;
#pragma unroll
  for (int i = 0; i < ACCT; ++i) {
    acc[i] = (f32x4){0.f, 0.f, 0.f, 0.f};
    if (i < nlive) {
      const short* kr = kbase + (size_t)((kt0 + i) * 16) * D_DIM;
      const bf16x8 b0 = *(const bf16x8*)kr;
      const bf16x8 b1 = *(const bf16x8*)(kr + 32);
      acc[i] = __builtin_amdgcn_mfma_f32_16x16x32_bf16(b0, qb0, acc[i], 0, 0, 0);
      acc[i] = __builtin_amdgcn_mfma_f32_16x16x32_bf16(b1, qb1, acc[i], 0, 0, 0);
    }
  }

  // ---- softmax: in-lane over 68 values + 2 shfls ----
  const int qr = q0 + w * 16 + c;
  const int kb = kstart + 4 * hi;
  float m = NEGBIG;
#pragma unroll
  for (int i = 0; i < ACCT; ++i)
    if (i < nlive) {
#pragma unroll
      for (int j = 0; j < 4; ++j) {
        float s = acc[i][j] * 0.125f;        // 1/sqrt(64)
        const int kcol = kb + (kt0 + i) * 16 + j;
        int dist = qr - kcol; dist = dist < 0 ? -dist : dist;
        s = (dist <= WIN) ? s : NEGBIG;
        acc[i][j] = s;
        m = fmaxf(m, s);
      }
    }
  m = fmaxf(m, __shfl_xor(m, 16));
  m = fmaxf(m, __shfl_xor(m, 32));
  float sum = 0.f;
#pragma unroll
  for (int i = 0; i < ACCT; ++i)
    if (i < nlive) {
#pragma unroll
      for (int j = 0; j < 4; ++j) {
        const float p = __expf(acc[i][j] - m);
        acc[i][j] = p;
        sum += p;
      }
    }
  sum += __shfl_xor(sum, 16);
  sum += __shfl_xor(sum, 32);
  const float inv = 1.f / sum;

  // ---- P(bf16) -> Pb (own wave's quarter only; no cross-wave use) ----
  const int prow = w * 16 + c;
#pragma unroll
  for (int i = 0; i < ACCT; ++i)
    if (i < nlive) {
      bf16x4 pk;
#pragma unroll
      for (int j = 0; j < 4; ++j) pk[j] = f2b(acc[i][j] * inv);
      *(bf16x4*)(Pb + swz(prow, 32 * (kt0 + i) + 8 * hi)) = pk;
    }
  {
    const bf16x4 z4 = {0, 0, 0, 0};
    for (int t = 0; t < kt0; ++t) *(bf16x4*)(Pb + swz(prow, 32 * t + 8 * hi)) = z4;
    for (int t = kt1; t < nkt; ++t) *(bf16x4*)(Pb + swz(prow, 32 * t + 8 * hi)) = z4;
  }

  // ---- O = P V : V^T B-frags straight from global (L2-resident window) ----
  f32x4 ov[4];
#pragma unroll
  for (int dt = 0; dt < 4; ++dt) ov[dt] = (f32x4){0.f, 0.f, 0.f, 0.f};
  for (int s = s0; s < s1; ++s) {
    const bf16x8 pa = *(const bf16x8*)(Pb + swz(w * 16 + c, 64 * s + 16 * hi));
#pragma unroll
    for (int dt = 0; dt < 4; ++dt) {
      const short* vp = Vt16 + ((size_t)(bh * D_DIM + dt * 16 + c)) * T_DIM +
                        kstart + 32 * s + 8 * hi;
      const bf16x8 vb = *(const bf16x8*)vp;
      ov[dt] = __builtin_amdgcn_mfma_f32_16x16x32_bf16(pa, vb, ov[dt], 0, 0, 0);
    }
  }
#pragma unroll
  for (int dt = 0; dt < 4; ++dt)
#pragma unroll
    for (int j = 0; j < 4; ++j)
      __builtin_nontemporal_store(
          ov[dt][j], optr + (size_t)(q0 + w * 16 + 4 * hi + j) * D_DIM + dt * 16 + c);

  // ---- row sweep last: pure store tail overlaps next block's compute ----
  for (int rr = 0; rr < 16; ++rr) {
    const int r = w * 16 + rr;
    float* dst = aptr + (size_t)(q0 + r) * T_DIM;
#pragma unroll
    for (int i = 0; i < 8; ++i) {
      const int col = i * 256 + lane * 4;
      f32x4 val = {0.f, 0.f, 0.f, 0.f};
      if (col >= kstart && col < kend) {
        const bf16x4 pv = *(const bf16x4*)(Pb + swz(r, (col - kstart) * 2));
        val[0] = b2f(pv[0]); val[1] = b2f(pv[1]); val[2] = b2f(pv[2]); val[3] = b2f(pv[3]);
      }
      __builtin_nontemporal_store(val, (f32x4*)(dst + col));
    }
  }
}

// ---------------- fallback (R7 kernel) if ws too small ----------------
__global__ __launch_bounds__(256, 2) void lsa_fb(
    const float* __restrict__ Qg, const float* __restrict__ Kg,
    const float* __restrict__ Vg, float* __restrict__ Og,
    float* __restrict__ Ag) {
  const int tid = threadIdx.x;
  const int work = ((blockIdx.x & 7) << 7) + (blockIdx.x >> 3);
  const int bh = work >> 5;
  const int q0 = (work & 31) * QBLK;
  int kstart = q0 - WIN; if (kstart < 0) kstart = 0;
  int kend = q0 + QBLK + WIN; if (kend > T_DIM) kend = T_DIM;
  const int KW = kend - kstart;
  const int nkt = KW >> 4;

  const float* qptr = Qg + (size_t)bh * (T_DIM * D_DIM);
  const float* kptr = Kg + (size_t)bh * (T_DIM * D_DIM);
  const float* vptr = Vg + (size_t)bh * (T_DIM * D_DIM);
  float* optr = Og + (size_t)bh * (T_DIM * D_DIM);
  float* aptr = Ag + (size_t)bh * ((size_t)T_DIM * T_DIM);

  __shared__ __align__(16) char Vb[D_DIM * 640];
  __shared__ __align__(16) char Pb[QBLK * 640];

  for (int idx = tid; idx < KW * 16; idx += 256) {
    const int r = idx >> 4, c4 = idx & 15;
    f32x4 f = *(const f32x4*)(vptr + (size_t)(kstart + r) * D_DIM + c4 * 4);
    const int d0 = c4 * 4;
    *(short*)(Vb + swz(d0 + 0, r * 2)) = f2b(f[0]);
    *(short*)(Vb + swz(d0 + 1, r * 2)) = f2b(f[1]);
    *(short*)(Vb + swz(d0 + 2, r * 2)) = f2b(f[2]);
    *(short*)(Vb + swz(d0 + 3, r * 2)) = f2b(f[3]);
  }

  const int lane = tid & 63, w = tid >> 6, c = lane & 15, hi = lane >> 4;
  const float* qrow = qptr + (size_t)(q0 + w * 16 + c) * D_DIM + 8 * hi;
  const bf16x8 qb0 = cvt8(*(const f32x4*)qrow, *(const f32x4*)(qrow + 4));
  const bf16x8 qb1 = cvt8(*(const f32x4*)(qrow + 32), *(const f32x4*)(qrow + 36));

  int klo = q0 + w * 16 - WIN - kstart; if (klo < 0) klo = 0;
  const int kt0 = klo >> 4;
  int kt1 = (q0 + w * 16 + 15 + WIN + 1 - kstart + 15) >> 4; if (kt1 > nkt) kt1 = nkt;
  const int s0 = kt0 >> 1, s1 = (kt1 + 1) >> 1;
  const int nlive = kt1 - kt0;

  f32x4 acc[ACCT];
#pragma unroll
  for (int i = 0; i < ACCT; ++i) {
    acc[i] = (f32x4){0.f, 0.f, 0.f, 0.f};
    if (i < nlive) {
      const float* kr = kptr + (size_t)(kstart + (kt0 + i) * 16 + c) * D_DIM + 8 * hi;
      const bf16x8 b0 = cvt8(*(const f32x4*)kr, *(const f32x4*)(kr + 4));
      const bf16x8 b1 = cvt8(*(const f32x4*)(kr + 32), *(const f32x4*)(kr + 36));
      acc[i] = __builtin_amdgcn_mfma_f32_16x16x32_bf16(b0, qb0, acc[i], 0, 0, 0);
      acc[i] = __builtin_amdgcn_mfma_f32_16x16x32_bf16(b1, qb1, acc[i], 0, 0, 0);
    }
  }

  const int qr = q0 + w * 16 + c;
  const int kb = kstart + 4 * hi;
  float m = NEGBIG;
#pragma unroll
  for (int i = 0; i < ACCT; ++i)
    if (i < nlive) {
#pragma unroll
      for (int j = 0; j < 4; ++j) {
        float s = acc[i][j] * 0.125f;
        const int kcol = kb + (kt0 + i) * 16 + j;
        int dist = qr - kcol; dist = dist < 0 ? -dist : dist;
        s = (dist <= WIN) ? s : NEGBIG;
        acc[i][j] = s;
        m = fmaxf(m, s);
      }
    }
  m = fmaxf(m, __shfl_xor(m, 16));
  m = fmaxf(m, __shfl_xor(m, 32));
  float sum = 0.f;
#pragma unroll
  for (int i = 0; i < ACCT; ++i)
    if (i < nlive) {
#pragma unroll
      for (int j = 0; j < 4; ++j) {
        const float p = __expf(acc[i][j] - m);
        acc[i][j] = p;
        sum += p;
      }
    }
  sum += __shfl_xor(sum, 16);
  sum += __shfl_xor(sum, 32);
  const float inv = 1.f / sum;

  const int prow = w * 16 + c;
#pragma unroll
  for (int i = 0; i < ACCT; ++i)
    if (i < nlive) {
      bf16x4 pk;
#pragma unroll
      for (int j = 0; j < 4; ++j) pk[j] = f2b(acc[i][j] * inv);
      *(bf16x4*)(Pb + swz(prow, 32 * (kt0 + i) + 8 * hi)) = pk;
    }
  {
    const bf16x4 z4 = {0, 0, 0, 0};
    for (int t = 0; t < kt0; ++t) *(bf16x4*)(Pb + swz(prow, 32 * t + 8 * hi)) = z4;
    for (int t = kt1; t < nkt; ++t) *(bf16x4*)(Pb + swz(prow, 32 * t + 8 * hi)) = z4;
  }

  for (int rr = 0; rr < 16; ++rr) {
    const int r = w * 16 + rr;
    float* dst = aptr + (size_t)(q0 + r) * T_DIM;
#pragma unroll
    for (int i = 0; i < 8; ++i) {
      const int col = i * 256 + lane * 4;
      f32x4 val = {0.f, 0.f, 0.f, 0.f};
      if (col >= kstart && col < kend) {
        const bf16x4 pv = *(const bf16x4*)(Pb + swz(r, (col - kstart) * 2));
        val[0] = b2f(pv[0]); val[1] = b2f(pv[1]); val[2] = b2f(pv[2]); val[3] = b2f(pv[3]);
      }
      __builtin_nontemporal_store(val, (f32x4*)(dst + col));
    }
  }

  __syncthreads();

  f32x4 ov[4];
#pragma unroll
  for (int dt = 0; dt < 4; ++dt) ov[dt] = (f32x4){0.f, 0.f, 0.f, 0.f};
  for (int s = s0; s < s1; ++s) {
    const bf16x8 pa = *(const bf16x8*)(Pb + swz(w * 16 + c, 64 * s + 16 * hi));
#pragma unroll
    for (int dt = 0; dt < 4; ++dt) {
      const bf16x8 vb = *(const bf16x8*)(Vb + swz(dt * 16 + c, 64 * s + 16 * hi));
      ov[dt] = __builtin_amdgcn_mfma_f32_16x16x32_bf16(pa, vb, ov[dt], 0, 0, 0);
    }
  }
#pragma unroll
  for (int dt = 0; dt < 4; ++dt)
#pragma unroll
    for (int j = 0; j < 4; ++j)
      __builtin_nontemporal_store(
          ov[dt][j], optr + (size_t)(q0 + w * 16 + 4 * hi + j) * D_DIM + dt * 16 + c);
}

extern "C" void kernel_launch(void* const* d_in, const int* in_sizes, int n_in,
                              void* d_out, int out_size, void* d_ws, size_t ws_size,
                              hipStream_t stream) {
  const float* q = (const float*)d_in[0];
  const float* k = (const float*)d_in[1];
  const float* v = (const float*)d_in[2];
  float* out = (float*)d_out;
  float* attn = out + (size_t)BH * T_DIM * D_DIM;  // output first, then attn

  const size_t need = (size_t)3 * NELEM * sizeof(short);  // 25.2 MB
  if (ws_size >= need) {
    short* q16 = (short*)d_ws;
    short* k16 = q16 + NELEM;
    short* vt16 = k16 + NELEM;
    conv_qk<<<dim3(NELEM / 8 / 256), dim3(256), 0, stream>>>(q, q16);
    conv_qk<<<dim3(NELEM / 8 / 256), dim3(256), 0, stream>>>(k, k16);
    conv_vt<<<dim3(BH * (T_DIM / 64)), dim3(256), 0, stream>>>(v, vt16);
    lsa_main<<<dim3(BH * (T_DIM / QBLK)), dim3(256), 0, stream>>>(q16, k16, vt16, out, attn);
  } else {
    lsa_fb<<<dim3(BH * (T_DIM / QBLK)), dim3(256), 0, stream>>>(q, k, v, out, attn);
  }
}

// Round 9
// 147.111 us; speedup vs baseline: 1.0436x; 1.0436x over previous
//
#include <hip/hip_runtime.h>
#include <hip/hip_bf16.h>

typedef short bf16x8 __attribute__((ext_vector_type(8)));
typedef short bf16x4 __attribute__((ext_vector_type(4)));
typedef float f32x4 __attribute__((ext_vector_type(4)));

#define T_DIM 2048
#define D_DIM 64
#define WIN 128
#define QBLK 64
#define ACCT 17          // max live 16-wide k-tiles per 16-row wave tile
#define NEGBIG -1e30f

__device__ __forceinline__ short f2b(float x) {
  __hip_bfloat16 h = __float2bfloat16(x);
  return *reinterpret_cast<short*>(&h);
}
__device__ __forceinline__ float b2f(short s) {
  unsigned u = ((unsigned)(unsigned short)s) << 16;
  return __builtin_bit_cast(float, u);
}
__device__ __forceinline__ bf16x8 cvt8(f32x4 a, f32x4 b) {
  bf16x8 r;
  r[0] = f2b(a[0]); r[1] = f2b(a[1]); r[2] = f2b(a[2]); r[3] = f2b(a[3]);
  r[4] = f2b(b[0]); r[5] = f2b(b[1]); r[6] = f2b(b[2]); r[7] = f2b(b[3]);
  return r;
}
// swizzled byte address in a 640B-row LDS tile
__device__ __forceinline__ int swz(int row, int b) { return row * 640 + (b ^ ((row & 7) << 4)); }

// ---- stage V window transposed into Vb (bf16, swizzled 640B rows) ----
__device__ __forceinline__ void stage_v(const float* __restrict__ vptr, char* Vb,
                                        int kstart, int KW, int tid) {
  for (int idx = tid; idx < KW * 16; idx += 256) {
    const int r = idx >> 4, c4 = idx & 15;
    f32x4 f = *(const f32x4*)(vptr + (size_t)(kstart + r) * D_DIM + c4 * 4);
    const int d0 = c4 * 4;
    *(short*)(Vb + swz(d0 + 0, r * 2)) = f2b(f[0]);
    *(short*)(Vb + swz(d0 + 1, r * 2)) = f2b(f[1]);
    *(short*)(Vb + swz(d0 + 2, r * 2)) = f2b(f[2]);
    *(short*)(Vb + swz(d0 + 3, r * 2)) = f2b(f[3]);
  }
}

// ---- S^T = K Q^T (swapped), softmax in-lane, P(bf16) -> Pb; returns live range ----
__device__ __forceinline__ void compute_smax_p(
    const float* __restrict__ qptr, const float* __restrict__ kptr, char* Pb,
    int q0, int kstart, int nkt, int w, int c, int hi, int& kt0o, int& kt1o) {
  const float* qrow = qptr + (size_t)(q0 + w * 16 + c) * D_DIM + 8 * hi;
  const bf16x8 qb0 = cvt8(*(const f32x4*)qrow, *(const f32x4*)(qrow + 4));
  const bf16x8 qb1 = cvt8(*(const f32x4*)(qrow + 32), *(const f32x4*)(qrow + 36));

  int klo = q0 + w * 16 - WIN - kstart; if (klo < 0) klo = 0;
  const int kt0 = klo >> 4;
  int kt1 = (q0 + w * 16 + 15 + WIN + 1 - kstart + 15) >> 4; if (kt1 > nkt) kt1 = nkt;
  const int nlive = kt1 - kt0;

  f32x4 acc[ACCT];
#pragma unroll
  for (int i = 0; i < ACCT; ++i) {
    acc[i] = (f32x4){0.f, 0.f, 0.f, 0.f};
    if (i < nlive) {
      const float* kr = kptr + (size_t)(kstart + (kt0 + i) * 16 + c) * D_DIM + 8 * hi;
      const bf16x8 b0 = cvt8(*(const f32x4*)kr, *(const f32x4*)(kr + 4));
      const bf16x8 b1 = cvt8(*(const f32x4*)(kr + 32), *(const f32x4*)(kr + 36));
      acc[i] = __builtin_amdgcn_mfma_f32_16x16x32_bf16(b0, qb0, acc[i], 0, 0, 0);
      acc[i] = __builtin_amdgcn_mfma_f32_16x16x32_bf16(b1, qb1, acc[i], 0, 0, 0);
    }
  }

  const int qr = q0 + w * 16 + c;
  const int kb = kstart + 4 * hi;
  float m = NEGBIG;
#pragma unroll
  for (int i = 0; i < ACCT; ++i)
    if (i < nlive) {
#pragma unroll
      for (int j = 0; j < 4; ++j) {
        float s = acc[i][j] * 0.125f;        // 1/sqrt(64)
        const int kcol = kb + (kt0 + i) * 16 + j;
        int dist = qr - kcol; dist = dist < 0 ? -dist : dist;
        s = (dist <= WIN) ? s : NEGBIG;
        acc[i][j] = s;
        m = fmaxf(m, s);
      }
    }
  m = fmaxf(m, __shfl_xor(m, 16));
  m = fmaxf(m, __shfl_xor(m, 32));
  float sum = 0.f;
#pragma unroll
  for (int i = 0; i < ACCT; ++i)
    if (i < nlive) {
#pragma unroll
      for (int j = 0; j < 4; ++j) {
        const float p = __expf(acc[i][j] - m);
        acc[i][j] = p;
        sum += p;
      }
    }
  sum += __shfl_xor(sum, 16);
  sum += __shfl_xor(sum, 32);
  const float inv = 1.f / sum;

  const int prow = w * 16 + c;
#pragma unroll
  for (int i = 0; i < ACCT; ++i)
    if (i < nlive) {
      bf16x4 pk;
#pragma unroll
      for (int j = 0; j < 4; ++j) pk[j] = f2b(acc[i][j] * inv);
      *(bf16x4*)(Pb + swz(prow, 32 * (kt0 + i) + 8 * hi)) = pk;
    }
  {
    const bf16x4 z4 = {0, 0, 0, 0};
    for (int t = 0; t < kt0; ++t) *(bf16x4*)(Pb + swz(prow, 32 * t + 8 * hi)) = z4;
    for (int t = kt1; t < nkt; ++t) *(bf16x4*)(Pb + swz(prow, 32 * t + 8 * hi)) = z4;
  }
  kt0o = kt0; kt1o = kt1;
}

// ---- O = P V + scattered O store ----
__device__ __forceinline__ void pv_store(const char* Pb, const char* Vb,
                                         float* __restrict__ optr, int q0,
                                         int kt0, int kt1, int w, int c, int hi) {
  const int s0 = kt0 >> 1, s1 = (kt1 + 1) >> 1;
  f32x4 ov[4];
#pragma unroll
  for (int dt = 0; dt < 4; ++dt) ov[dt] = (f32x4){0.f, 0.f, 0.f, 0.f};
  for (int s = s0; s < s1; ++s) {
    const bf16x8 pa = *(const bf16x8*)(Pb + swz(w * 16 + c, 64 * s + 16 * hi));
#pragma unroll
    for (int dt = 0; dt < 4; ++dt) {
      const bf16x8 vb = *(const bf16x8*)(Vb + swz(dt * 16 + c, 64 * s + 16 * hi));
      ov[dt] = __builtin_amdgcn_mfma_f32_16x16x32_bf16(pa, vb, ov[dt], 0, 0, 0);
    }
  }
#pragma unroll
  for (int dt = 0; dt < 4; ++dt)
#pragma unroll
    for (int j = 0; j < 4; ++j)
      __builtin_nontemporal_store(
          ov[dt][j], optr + (size_t)(q0 + w * 16 + 4 * hi + j) * D_DIM + dt * 16 + c);
}

// ---- full-row sweep: zeros + band from Pb, sequential f32x4 stores ----
__device__ __forceinline__ void sweep_rows(float* __restrict__ aptr, const char* Pb,
                                           int q0, int kstart, int kend, int w, int lane) {
  for (int rr = 0; rr < 16; ++rr) {
    const int r = w * 16 + rr;
    float* dst = aptr + (size_t)(q0 + r) * T_DIM;
#pragma unroll
    for (int i = 0; i < 8; ++i) {
      const int col = i * 256 + lane * 4;
      f32x4 val = {0.f, 0.f, 0.f, 0.f};
      if (col >= kstart && col < kend) {
        const bf16x4 pv = *(const bf16x4*)(Pb + swz(r, (col - kstart) * 2));
        val[0] = b2f(pv[0]); val[1] = b2f(pv[1]); val[2] = b2f(pv[2]); val[3] = b2f(pv[3]);
      }
      __builtin_nontemporal_store(val, (f32x4*)(dst + col));
    }
  }
}

__global__ __launch_bounds__(256, 2) void lsa_pair(
    const float* __restrict__ Qg, const float* __restrict__ Kg,
    const float* __restrict__ Vg, float* __restrict__ Og,
    float* __restrict__ Ag) {
  const int tid = threadIdx.x;
  // XCD-chunked swizzle over 512 pairs: XCD x owns pairs [64x, 64x+64) = 4 bh
  const int pair = ((blockIdx.x & 7) << 6) + (blockIdx.x >> 3);
  const int bh = pair >> 4;
  const int q0A = (pair & 15) * (2 * QBLK);
  const int q0B = q0A + QBLK;

  const float* qptr = Qg + (size_t)bh * (T_DIM * D_DIM);
  const float* kptr = Kg + (size_t)bh * (T_DIM * D_DIM);
  const float* vptr = Vg + (size_t)bh * (T_DIM * D_DIM);
  float* optr = Og + (size_t)bh * (T_DIM * D_DIM);
  float* aptr = Ag + (size_t)bh * ((size_t)T_DIM * T_DIM);

  // LDS: Vb 40KB (reused A->B) + Pb 40KB (rows wave-private) = 80KB -> 2 blocks/CU
  __shared__ __align__(16) char Vb[D_DIM * 640];
  __shared__ __align__(16) char Pb[QBLK * 640];

  const int lane = tid & 63, w = tid >> 6, c = lane & 15, hi = lane >> 4;

  int kstartA = q0A - WIN; if (kstartA < 0) kstartA = 0;
  int kendA = q0A + QBLK + WIN; if (kendA > T_DIM) kendA = T_DIM;
  const int nktA = (kendA - kstartA) >> 4;
  int kstartB = q0B - WIN; if (kstartB < 0) kstartB = 0;
  int kendB = q0B + QBLK + WIN; if (kendB > T_DIM) kendB = T_DIM;
  const int nktB = (kendB - kstartB) >> 4;

  // ================= work A =================
  stage_v(vptr, Vb, kstartA, kendA - kstartA, tid);
  int kt0A, kt1A;
  compute_smax_p(qptr, kptr, Pb, q0A, kstartA, nktA, w, c, hi, kt0A, kt1A);
  __syncthreads();                       // b1: Vb(A) ready
  pv_store(Pb, Vb, optr, q0A, kt0A, kt1A, w, c, hi);
  __syncthreads();                       // b2: Vb(A) consumption done

  // ================= work B (loads) over sweep A (stores) =================
  stage_v(vptr, Vb, kstartB, kendB - kstartB, tid);   // issue early, consumed after b3
  int kt0B, kt1B;
  {
    // S(B)+softmax(B) loads/compute issued before sweep-A stores...
    const float* qrow = qptr + (size_t)(q0B + w * 16 + c) * D_DIM + 8 * hi;
    const bf16x8 qb0 = cvt8(*(const f32x4*)qrow, *(const f32x4*)(qrow + 4));
    const bf16x8 qb1 = cvt8(*(const f32x4*)(qrow + 32), *(const f32x4*)(qrow + 36));
    int klo = q0B + w * 16 - WIN - kstartB; if (klo < 0) klo = 0;
    const int kt0 = klo >> 4;
    int kt1 = (q0B + w * 16 + 15 + WIN + 1 - kstartB + 15) >> 4; if (kt1 > nktB) kt1 = nktB;
    const int nlive = kt1 - kt0;
    f32x4 acc[ACCT];
#pragma unroll
    for (int i = 0; i < ACCT; ++i) {
      acc[i] = (f32x4){0.f, 0.f, 0.f, 0.f};
      if (i < nlive) {
        const float* kr = kptr + (size_t)(kstartB + (kt0 + i) * 16 + c) * D_DIM + 8 * hi;
        const bf16x8 b0 = cvt8(*(const f32x4*)kr, *(const f32x4*)(kr + 4));
        const bf16x8 b1 = cvt8(*(const f32x4*)(kr + 32), *(const f32x4*)(kr + 36));
        acc[i] = __builtin_amdgcn_mfma_f32_16x16x32_bf16(b0, qb0, acc[i], 0, 0, 0);
        acc[i] = __builtin_amdgcn_mfma_f32_16x16x32_bf16(b1, qb1, acc[i], 0, 0, 0);
      }
    }
    const int qr = q0B + w * 16 + c;
    const int kb = kstartB + 4 * hi;
    float m = NEGBIG;
#pragma unroll
    for (int i = 0; i < ACCT; ++i)
      if (i < nlive) {
#pragma unroll
        for (int j = 0; j < 4; ++j) {
          float s = acc[i][j] * 0.125f;
          const int kcol = kb + (kt0 + i) * 16 + j;
          int dist = qr - kcol; dist = dist < 0 ? -dist : dist;
          s = (dist <= WIN) ? s : NEGBIG;
          acc[i][j] = s;
          m = fmaxf(m, s);
        }
      }
    m = fmaxf(m, __shfl_xor(m, 16));
    m = fmaxf(m, __shfl_xor(m, 32));
    float sum = 0.f;
#pragma unroll
    for (int i = 0; i < ACCT; ++i)
      if (i < nlive) {
#pragma unroll
        for (int j = 0; j < 4; ++j) {
          const float p = __expf(acc[i][j] - m);
          acc[i][j] = p;
          sum += p;
        }
      }
    sum += __shfl_xor(sum, 16);
    sum += __shfl_xor(sum, 32);
    const float inv = 1.f / sum;

    // ...then sweep A's 512KB store stream drains under the rest of B
    sweep_rows(aptr, Pb, q0A, kstartA, kendA, w, lane);

    // P(B) -> Pb after sweep(A) reads (same-wave LDS order; rows wave-private)
    const int prow = w * 16 + c;
#pragma unroll
    for (int i = 0; i < ACCT; ++i)
      if (i < nlive) {
        bf16x4 pk;
#pragma unroll
        for (int j = 0; j < 4; ++j) pk[j] = f2b(acc[i][j] * inv);
        *(bf16x4*)(Pb + swz(prow, 32 * (kt0 + i) + 8 * hi)) = pk;
      }
    {
      const bf16x4 z4 = {0, 0, 0, 0};
      for (int t = 0; t < kt0; ++t) *(bf16x4*)(Pb + swz(prow, 32 * t + 8 * hi)) = z4;
      for (int t = kt1; t < nktB; ++t) *(bf16x4*)(Pb + swz(prow, 32 * t + 8 * hi)) = z4;
    }
    kt0B = kt0; kt1B = kt1;
  }
  __syncthreads();                       // b3: Vb(B) ready
  pv_store(Pb, Vb, optr, q0B, kt0B, kt1B, w, c, hi);
  sweep_rows(aptr, Pb, q0B, kstartB, kendB, w, lane);
}

extern "C" void kernel_launch(void* const* d_in, const int* in_sizes, int n_in,
                              void* d_out, int out_size, void* d_ws, size_t ws_size,
                              hipStream_t stream) {
  const float* q = (const float*)d_in[0];
  const float* k = (const float*)d_in[1];
  const float* v = (const float*)d_in[2];
  float* out = (float*)d_out;
  float* attn = out + (size_t)2 * 16 * T_DIM * D_DIM;  // output first, then attn
  lsa_pair<<<dim3(2 * 16 * (T_DIM / (2 * QBLK))), dim3(256), 0, stream>>>(q, k, v, out, attn);
}

// Round 10
// 139.672 us; speedup vs baseline: 1.0991x; 1.0533x over previous
//
#include <hip/hip_runtime.h>
#include <hip/hip_bf16.h>

typedef short bf16x8 __attribute__((ext_vector_type(8)));
typedef short bf16x4 __attribute__((ext_vector_type(4)));
typedef float f32x4 __attribute__((ext_vector_type(4)));

#define T_DIM 2048
#define D_DIM 64
#define WIN 128
#define QBLK 64
#define ACCT 17          // max live 16-wide k-tiles per 16-row wave tile
#define NEGBIG -1e30f

__device__ __forceinline__ short f2b(float x) {
  __hip_bfloat16 h = __float2bfloat16(x);
  return *reinterpret_cast<short*>(&h);
}
__device__ __forceinline__ float b2f(short s) {
  unsigned u = ((unsigned)(unsigned short)s) << 16;
  return __builtin_bit_cast(float, u);
}
__device__ __forceinline__ bf16x8 cvt8(f32x4 a, f32x4 b) {
  bf16x8 r;
  r[0] = f2b(a[0]); r[1] = f2b(a[1]); r[2] = f2b(a[2]); r[3] = f2b(a[3]);
  r[4] = f2b(b[0]); r[5] = f2b(b[1]); r[6] = f2b(b[2]); r[7] = f2b(b[3]);
  return r;
}
// swizzled byte address in a 640B-row LDS tile
__device__ __forceinline__ int swz(int row, int b) { return row * 640 + (b ^ ((row & 7) << 4)); }

__global__ __launch_bounds__(256, 2) void lsa_one(
    const float* __restrict__ Qg, const float* __restrict__ Kg,
    const float* __restrict__ Vg, float* __restrict__ Og,
    float* __restrict__ Ag) {
  const int tid = threadIdx.x;
  // XCD-chunked swizzle: XCD x hosts works [128x,128x+128) = 4 bh, 32 q-blocks
  const int work = ((blockIdx.x & 7) << 7) + (blockIdx.x >> 3);
  const int bh = work >> 5;
  const int q0 = (work & 31) * QBLK;
  int kstart = q0 - WIN; if (kstart < 0) kstart = 0;
  int kend = q0 + QBLK + WIN; if (kend > T_DIM) kend = T_DIM;
  const int KW = kend - kstart;   // 192/256/320
  const int nkt = KW >> 4;

  const float* qptr = Qg + (size_t)bh * (T_DIM * D_DIM);
  const float* kptr = Kg + (size_t)bh * (T_DIM * D_DIM);
  const float* vptr = Vg + (size_t)bh * (T_DIM * D_DIM);
  float* optr = Og + (size_t)bh * (T_DIM * D_DIM);
  float* aptr = Ag + (size_t)bh * ((size_t)T_DIM * T_DIM);

  // LDS: Vt 40KB + P band 40KB = 80KB -> 2 blocks/CU
  __shared__ __align__(16) char Vb[D_DIM * 640];
  __shared__ __align__(16) char Pb[QBLK * 640];

  // ---- stage V transposed: Vt[d][k] bf16 (no barrier yet; consumed by PV) ----
  for (int idx = tid; idx < KW * 16; idx += 256) {
    const int r = idx >> 4, c4 = idx & 15;
    f32x4 f = *(const f32x4*)(vptr + (size_t)(kstart + r) * D_DIM + c4 * 4);
    const int d0 = c4 * 4;
    *(short*)(Vb + swz(d0 + 0, r * 2)) = f2b(f[0]);
    *(short*)(Vb + swz(d0 + 1, r * 2)) = f2b(f[1]);
    *(short*)(Vb + swz(d0 + 2, r * 2)) = f2b(f[2]);
    *(short*)(Vb + swz(d0 + 3, r * 2)) = f2b(f[3]);
  }

  const int lane = tid & 63, w = tid >> 6, c = lane & 15, hi = lane >> 4;

  // Q B-frag (swapped QK^T): lane holds Q row q0+w*16+c, d-slices
  const float* qrow = qptr + (size_t)(q0 + w * 16 + c) * D_DIM + 8 * hi;
  const bf16x8 qb0 = cvt8(*(const f32x4*)qrow, *(const f32x4*)(qrow + 4));
  const bf16x8 qb1 = cvt8(*(const f32x4*)(qrow + 32), *(const f32x4*)(qrow + 36));

  // per-wave live tile range
  int klo = q0 + w * 16 - WIN - kstart; if (klo < 0) klo = 0;
  const int kt0 = klo >> 4;
  int kt1 = (q0 + w * 16 + 15 + WIN + 1 - kstart + 15) >> 4; if (kt1 > nkt) kt1 = nkt;
  const int s0 = kt0 >> 1, s1 = (kt1 + 1) >> 1;
  const int nlive = kt1 - kt0;

  // ---- S^T = K Q^T over live tiles: lane (c,hi) owns q-row c, k = 16i+4hi+j ----
  f32x4 acc[ACCT];
#pragma unroll
  for (int i = 0; i < ACCT; ++i) {
    acc[i] = (f32x4){0.f, 0.f, 0.f, 0.f};
    if (i < nlive) {
      const float* kr = kptr + (size_t)(kstart + (kt0 + i) * 16 + c) * D_DIM + 8 * hi;
      const bf16x8 b0 = cvt8(*(const f32x4*)kr, *(const f32x4*)(kr + 4));
      const bf16x8 b1 = cvt8(*(const f32x4*)(kr + 32), *(const f32x4*)(kr + 36));
      acc[i] = __builtin_amdgcn_mfma_f32_16x16x32_bf16(b0, qb0, acc[i], 0, 0, 0);
      acc[i] = __builtin_amdgcn_mfma_f32_16x16x32_bf16(b1, qb1, acc[i], 0, 0, 0);
    }
  }

  // ---- softmax: in-lane over 68 values, then 2 shfls across hi-groups ----
  const int qr = q0 + w * 16 + c;            // this lane's q-row
  const int kb = kstart + 4 * hi;
  float m = NEGBIG;
#pragma unroll
  for (int i = 0; i < ACCT; ++i)
    if (i < nlive) {
#pragma unroll
      for (int j = 0; j < 4; ++j) {
        float s = acc[i][j] * 0.125f;        // 1/sqrt(64)
        const int kcol = kb + (kt0 + i) * 16 + j;
        int dist = qr - kcol; dist = dist < 0 ? -dist : dist;
        s = (dist <= WIN) ? s : NEGBIG;
        acc[i][j] = s;
        m = fmaxf(m, s);
      }
    }
  m = fmaxf(m, __shfl_xor(m, 16));
  m = fmaxf(m, __shfl_xor(m, 32));
  float sum = 0.f;
#pragma unroll
  for (int i = 0; i < ACCT; ++i)
    if (i < nlive) {
#pragma unroll
      for (int j = 0; j < 4; ++j) {
        const float p = __expf(acc[i][j] - m);
        acc[i][j] = p;
        sum += p;
      }
    }
  sum += __shfl_xor(sum, 16);
  sum += __shfl_xor(sum, 32);
  const float inv = 1.f / sum;

  // ---- P(bf16) -> Pb: one ds_write_b64 per live tile ----
  const int prow = w * 16 + c;
#pragma unroll
  for (int i = 0; i < ACCT; ++i)
    if (i < nlive) {
      bf16x4 pk;
#pragma unroll
      for (int j = 0; j < 4; ++j) pk[j] = f2b(acc[i][j] * inv);
      *(bf16x4*)(Pb + swz(prow, 32 * (kt0 + i) + 8 * hi)) = pk;
    }
  {
    const bf16x4 z4 = {0, 0, 0, 0};
    for (int t = 0; t < kt0; ++t) *(bf16x4*)(Pb + swz(prow, 32 * t + 8 * hi)) = z4;
    for (int t = kt1; t < nkt; ++t) *(bf16x4*)(Pb + swz(prow, 32 * t + 8 * hi)) = z4;
  }

  // ---- row sweep: full 8KB rows, zeros + band, plain stores (through L2) ----
  for (int rr = 0; rr < 16; ++rr) {
    const int r = w * 16 + rr;
    float* dst = aptr + (size_t)(q0 + r) * T_DIM;
#pragma unroll
    for (int i = 0; i < 8; ++i) {
      const int col = i * 256 + lane * 4;
      f32x4 val = {0.f, 0.f, 0.f, 0.f};
      if (col >= kstart && col < kend) {
        const bf16x4 pv = *(const bf16x4*)(Pb + swz(r, (col - kstart) * 2));
        val[0] = b2f(pv[0]); val[1] = b2f(pv[1]); val[2] = b2f(pv[2]); val[3] = b2f(pv[3]);
      }
      *(f32x4*)(dst + col) = val;
    }
  }

  __syncthreads();   // only barrier: Vt ready for PV

  // ---- O = P V ----
  f32x4 ov[4];
#pragma unroll
  for (int dt = 0; dt < 4; ++dt) ov[dt] = (f32x4){0.f, 0.f, 0.f, 0.f};
  for (int s = s0; s < s1; ++s) {
    const bf16x8 pa = *(const bf16x8*)(Pb + swz(w * 16 + c, 64 * s + 16 * hi));
#pragma unroll
    for (int dt = 0; dt < 4; ++dt) {
      const bf16x8 vb = *(const bf16x8*)(Vb + swz(dt * 16 + c, 64 * s + 16 * hi));
      ov[dt] = __builtin_amdgcn_mfma_f32_16x16x32_bf16(pa, vb, ov[dt], 0, 0, 0);
    }
  }

  // ---- O store: bounce through own Pb quarter -> 4 contiguous 1KB wave-stores ----
  {
    float* ob = (float*)(Pb + w * 10240);   // wave-private, Pb reads all done
#pragma unroll
    for (int dt = 0; dt < 4; ++dt)
#pragma unroll
      for (int j = 0; j < 4; ++j)
        ob[(4 * hi + j) * 68 + dt * 16 + c] = ov[dt][j];   // 68-word rows: 2-way free
    float* obase = optr + (size_t)(q0 + w * 16) * D_DIM;
#pragma unroll
    for (int i = 0; i < 4; ++i) {
      const int p = i * 256 + lane * 4;
      const int r = p >> 6, col = p & 63;
      const f32x4 o4 = *(const f32x4*)(ob + r * 68 + col);
      *(f32x4*)(obase + p) = o4;
    }
  }
}

extern "C" void kernel_launch(void* const* d_in, const int* in_sizes, int n_in,
                              void* d_out, int out_size, void* d_ws, size_t ws_size,
                              hipStream_t stream) {
  const float* q = (const float*)d_in[0];
  const float* k = (const float*)d_in[1];
  const float* v = (const float*)d_in[2];
  float* out = (float*)d_out;
  float* attn = out + (size_t)2 * 16 * T_DIM * D_DIM;  // output first, then attn
  lsa_one<<<dim3(2 * 16 * (T_DIM / QBLK)), dim3(256), 0, stream>>>(q, k, v, out, attn);
}

// Round 11
// 128.412 us; speedup vs baseline: 1.1955x; 1.0877x over previous
//
#include <hip/hip_runtime.h>
#include <hip/hip_bf16.h>

typedef short bf16x8 __attribute__((ext_vector_type(8)));
typedef short bf16x4 __attribute__((ext_vector_type(4)));
typedef float f32x4 __attribute__((ext_vector_type(4)));

#define T_DIM 2048
#define D_DIM 64
#define WIN 128
#define QBLK 64
#define ACCT 17          // max live 16-wide k-tiles per 16-row wave tile
#define NEGBIG -1e30f

__device__ __forceinline__ short f2b(float x) {
  __hip_bfloat16 h = __float2bfloat16(x);
  return *reinterpret_cast<short*>(&h);
}
__device__ __forceinline__ float b2f(short s) {
  unsigned u = ((unsigned)(unsigned short)s) << 16;
  return __builtin_bit_cast(float, u);
}
__device__ __forceinline__ bf16x8 cvt8(f32x4 a, f32x4 b) {
  bf16x8 r;
  r[0] = f2b(a[0]); r[1] = f2b(a[1]); r[2] = f2b(a[2]); r[3] = f2b(a[3]);
  r[4] = f2b(b[0]); r[5] = f2b(b[1]); r[6] = f2b(b[2]); r[7] = f2b(b[3]);
  return r;
}
// swizzled byte address in a 640B-row LDS tile
__device__ __forceinline__ int swz(int row, int b) { return row * 640 + (b ^ ((row & 7) << 4)); }

__global__ __launch_bounds__(256, 2) void lsa_one(
    const float* __restrict__ Qg, const float* __restrict__ Kg,
    const float* __restrict__ Vg, float* __restrict__ Og,
    float* __restrict__ Ag) {
  const int tid = threadIdx.x;
  // XCD-chunked swizzle: XCD x hosts works [128x,128x+128) = 4 bh, 32 q-blocks
  const int work = ((blockIdx.x & 7) << 7) + (blockIdx.x >> 3);
  const int bh = work >> 5;
  const int q0 = (work & 31) * QBLK;
  int kstart = q0 - WIN; if (kstart < 0) kstart = 0;
  int kend = q0 + QBLK + WIN; if (kend > T_DIM) kend = T_DIM;
  const int KW = kend - kstart;   // 192/256/320
  const int nkt = KW >> 4;

  const float* qptr = Qg + (size_t)bh * (T_DIM * D_DIM);
  const float* kptr = Kg + (size_t)bh * (T_DIM * D_DIM);
  const float* vptr = Vg + (size_t)bh * (T_DIM * D_DIM);
  float* optr = Og + (size_t)bh * (T_DIM * D_DIM);
  float* aptr = Ag + (size_t)bh * ((size_t)T_DIM * T_DIM);

  // LDS: Vt 40KB + P band 40KB = 80KB -> 2 blocks/CU
  __shared__ __align__(16) char Vb[D_DIM * 640];
  __shared__ __align__(16) char Pb[QBLK * 640];

  // ---- stage V transposed: Vt[d][k] bf16 (no barrier yet; consumed by PV) ----
  for (int idx = tid; idx < KW * 16; idx += 256) {
    const int r = idx >> 4, c4 = idx & 15;
    f32x4 f = *(const f32x4*)(vptr + (size_t)(kstart + r) * D_DIM + c4 * 4);
    const int d0 = c4 * 4;
    *(short*)(Vb + swz(d0 + 0, r * 2)) = f2b(f[0]);
    *(short*)(Vb + swz(d0 + 1, r * 2)) = f2b(f[1]);
    *(short*)(Vb + swz(d0 + 2, r * 2)) = f2b(f[2]);
    *(short*)(Vb + swz(d0 + 3, r * 2)) = f2b(f[3]);
  }

  const int lane = tid & 63, w = tid >> 6, c = lane & 15, hi = lane >> 4;

  // Q B-frag (swapped QK^T): lane holds Q row q0+w*16+c, d-slices
  const float* qrow = qptr + (size_t)(q0 + w * 16 + c) * D_DIM + 8 * hi;
  const bf16x8 qb0 = cvt8(*(const f32x4*)qrow, *(const f32x4*)(qrow + 4));
  const bf16x8 qb1 = cvt8(*(const f32x4*)(qrow + 32), *(const f32x4*)(qrow + 36));

  // per-wave live tile range
  int klo = q0 + w * 16 - WIN - kstart; if (klo < 0) klo = 0;
  const int kt0 = klo >> 4;
  int kt1 = (q0 + w * 16 + 15 + WIN + 1 - kstart + 15) >> 4; if (kt1 > nkt) kt1 = nkt;
  const int s0 = kt0 >> 1, s1 = (kt1 + 1) >> 1;
  const int nlive = kt1 - kt0;

  // ---- S^T = K Q^T over live tiles: lane (c,hi) owns q-row c, k = 16i+4hi+j ----
  f32x4 acc[ACCT];
#pragma unroll
  for (int i = 0; i < ACCT; ++i) {
    acc[i] = (f32x4){0.f, 0.f, 0.f, 0.f};
    if (i < nlive) {
      const float* kr = kptr + (size_t)(kstart + (kt0 + i) * 16 + c) * D_DIM + 8 * hi;
      const bf16x8 b0 = cvt8(*(const f32x4*)kr, *(const f32x4*)(kr + 4));
      const bf16x8 b1 = cvt8(*(const f32x4*)(kr + 32), *(const f32x4*)(kr + 36));
      acc[i] = __builtin_amdgcn_mfma_f32_16x16x32_bf16(b0, qb0, acc[i], 0, 0, 0);
      acc[i] = __builtin_amdgcn_mfma_f32_16x16x32_bf16(b1, qb1, acc[i], 0, 0, 0);
    }
  }

  // ---- early zero sweep: out-of-band columns, zero data deps ----
  // All this block's global LOADS are already issued above; in-order vmcnt
  // retirement means subsequent load-waits don't wait on these stores.
  {
    const f32x4 zv = {0.f, 0.f, 0.f, 0.f};
    for (int rr = 0; rr < 16; ++rr) {
      float* dst = aptr + (size_t)(q0 + w * 16 + rr) * T_DIM;
      for (int col = lane * 4; col < kstart; col += 256)
        __builtin_nontemporal_store(zv, (f32x4*)(dst + col));
      for (int col = kend + lane * 4; col < T_DIM; col += 256)
        __builtin_nontemporal_store(zv, (f32x4*)(dst + col));
    }
  }

  // ---- softmax: in-lane over 68 values, then 2 shfls across hi-groups ----
  const int qr = q0 + w * 16 + c;            // this lane's q-row
  const int kb = kstart + 4 * hi;
  float m = NEGBIG;
#pragma unroll
  for (int i = 0; i < ACCT; ++i)
    if (i < nlive) {
#pragma unroll
      for (int j = 0; j < 4; ++j) {
        float s = acc[i][j] * 0.125f;        // 1/sqrt(64)
        const int kcol = kb + (kt0 + i) * 16 + j;
        int dist = qr - kcol; dist = dist < 0 ? -dist : dist;
        s = (dist <= WIN) ? s : NEGBIG;
        acc[i][j] = s;
        m = fmaxf(m, s);
      }
    }
  m = fmaxf(m, __shfl_xor(m, 16));
  m = fmaxf(m, __shfl_xor(m, 32));
  float sum = 0.f;
#pragma unroll
  for (int i = 0; i < ACCT; ++i)
    if (i < nlive) {
#pragma unroll
      for (int j = 0; j < 4; ++j) {
        const float p = __expf(acc[i][j] - m);
        acc[i][j] = p;
        sum += p;
      }
    }
  sum += __shfl_xor(sum, 16);
  sum += __shfl_xor(sum, 32);
  const float inv = 1.f / sum;

  // ---- P(bf16) -> Pb: one ds_write_b64 per live tile ----
  const int prow = w * 16 + c;
#pragma unroll
  for (int i = 0; i < ACCT; ++i)
    if (i < nlive) {
      bf16x4 pk;
#pragma unroll
      for (int j = 0; j < 4; ++j) pk[j] = f2b(acc[i][j] * inv);
      *(bf16x4*)(Pb + swz(prow, 32 * (kt0 + i) + 8 * hi)) = pk;
    }
  {
    const bf16x4 z4 = {0, 0, 0, 0};
    for (int t = 0; t < kt0; ++t) *(bf16x4*)(Pb + swz(prow, 32 * t + 8 * hi)) = z4;
    for (int t = kt1; t < nkt; ++t) *(bf16x4*)(Pb + swz(prow, 32 * t + 8 * hi)) = z4;
  }

  // ---- band sweep: only KW cols per row, contiguous nt stores ----
  for (int rr = 0; rr < 16; ++rr) {
    const int r = w * 16 + rr;
    float* dst = aptr + (size_t)(q0 + r) * T_DIM + kstart;
#pragma unroll
    for (int i = 0; i < 5; ++i) {
      const int off = i * 256 + lane * 4;
      if (off < KW) {
        const bf16x4 pv = *(const bf16x4*)(Pb + swz(r, off * 2));
        f32x4 val;
        val[0] = b2f(pv[0]); val[1] = b2f(pv[1]); val[2] = b2f(pv[2]); val[3] = b2f(pv[3]);
        __builtin_nontemporal_store(val, (f32x4*)(dst + off));
      }
    }
  }

  __syncthreads();   // only barrier: Vt ready for PV

  // ---- O = P V ----
  f32x4 ov[4];
#pragma unroll
  for (int dt = 0; dt < 4; ++dt) ov[dt] = (f32x4){0.f, 0.f, 0.f, 0.f};
  for (int s = s0; s < s1; ++s) {
    const bf16x8 pa = *(const bf16x8*)(Pb + swz(w * 16 + c, 64 * s + 16 * hi));
#pragma unroll
    for (int dt = 0; dt < 4; ++dt) {
      const bf16x8 vb = *(const bf16x8*)(Vb + swz(dt * 16 + c, 64 * s + 16 * hi));
      ov[dt] = __builtin_amdgcn_mfma_f32_16x16x32_bf16(pa, vb, ov[dt], 0, 0, 0);
    }
  }
#pragma unroll
  for (int dt = 0; dt < 4; ++dt)
#pragma unroll
    for (int j = 0; j < 4; ++j)
      __builtin_nontemporal_store(
          ov[dt][j], optr + (size_t)(q0 + w * 16 + 4 * hi + j) * D_DIM + dt * 16 + c);
}

extern "C" void kernel_launch(void* const* d_in, const int* in_sizes, int n_in,
                              void* d_out, int out_size, void* d_ws, size_t ws_size,
                              hipStream_t stream) {
  const float* q = (const float*)d_in[0];
  const float* k = (const float*)d_in[1];
  const float* v = (const float*)d_in[2];
  float* out = (float*)d_out;
  float* attn = out + (size_t)2 * 16 * T_DIM * D_DIM;  // output first, then attn
  lsa_one<<<dim3(2 * 16 * (T_DIM / QBLK)), dim3(256), 0, stream>>>(q, k, v, out, attn);
}